// Round 15
// baseline (388.045 us; speedup 1.0000x reference)
//
#include <hip/hip_runtime.h>
#include <hip/hip_bf16.h>
#include <stdint.h>

#define N_USER 100000
#define M_ITEM 50000
#define N_NODE 150000
#define B_SEED 2048
#define S_NB 20
#define TILES_U 782          // ceil(100000/128)
#define TILES_I 391          // ceil(50000/128)
#define NCH_U 9              // 576 cols / 64
#define NCH_I 21             // 1344 cols / 64

typedef __bf16   bf16x8 __attribute__((ext_vector_type(8)));
typedef float    f32x4  __attribute__((ext_vector_type(4)));
typedef uint32_t u32x4  __attribute__((ext_vector_type(4)));

typedef __attribute__((address_space(3))) uint32_t lds_u32_t;
typedef __attribute__((address_space(1))) const uint32_t glb_u32_t;

__device__ __forceinline__ uint16_t f2bf(float f) {
    uint32_t u = __float_as_uint(f);
    return (uint16_t)((u + 0x7FFFu + ((u >> 16) & 1u)) >> 16);   // RNE
}
__device__ __forceinline__ uint32_t pk2(float a, float b) {      // packed HW cvt (RNE)
    __hip_bfloat162 h = __float22bfloat162_rn(make_float2(a, b));
    return *reinterpret_cast<uint32_t*>(&h);
}
__device__ __forceinline__ float bf2f(uint16_t u) {
    return __uint_as_float(((uint32_t)u) << 16);
}

union BF8 { bf16x8 v; uint32_t u[4]; };

__device__ __forceinline__ uint4 packrow(const float* p) {
    const f32x4 a = *(const f32x4*)p, b = *(const f32x4*)(p + 4);
    return make_uint4(pk2(a[0], a[1]), pk2(a[2], a[3]),
                      pk2(b[0], b[1]), pk2(b[2], b[3]));
}
__device__ __forceinline__ uint4 maskrow(const float* p, int j0, int lim) {
    float v[8];
#pragma unroll
    for (int h = 0; h < 8; ++h) v[h] = (j0 + h < lim) ? p[j0 + h] : 0.f;
    return make_uint4(pk2(v[0], v[1]), pk2(v[2], v[3]),
                      pk2(v[4], v[5]), pk2(v[6], v[7]));
}

// ---------------------------------------------------------------------------
// prep: permuted-K transposed weights (bf16). k' order (matches Apack cols):
// [0,64) feat | [64,160) text | [160,192) numeric(10) | [192,224) w300 tail(12)
// [224,288) id | [288,576) w300 0..287 | [576,1344) s768 (items)
// ---------------------------------------------------------------------------
__global__ void prep_kernel(const float* __restrict__ Wproj_u, const float* __restrict__ Wnum_u,
                            const float* __restrict__ Wproj_i, const float* __restrict__ Wnum_i,
                            const float* __restrict__ Wv0, const float* __restrict__ Ww0,
                            uint16_t* __restrict__ WTU, uint16_t* __restrict__ WTI,
                            uint16_t* __restrict__ WvT, uint16_t* __restrict__ WwT)
{
    const int idx = blockIdx.x * 256 + threadIdx.x;   // exactly 135168
    if (idx < 36864) {
        const int d = idx / 576, kp = idx - d * 576;
        float v = 0.f;
        if (kp < 160)      v = Wproj_u[(64 + kp) * 64 + d];
        else if (kp < 192) { const int j = kp - 160; if (j < 10) v = Wnum_u[j * 64 + d]; }
        else if (kp < 224) { const int j = kp - 192; if (j < 12) v = Wproj_u[(512 + j) * 64 + d]; }
        else if (kp < 288) v = Wproj_u[(kp - 224) * 64 + d];
        else               v = Wproj_u[(224 + kp - 288) * 64 + d];
        WTU[d * 576 + kp] = f2bf(v);
    } else if (idx < 122880) {
        const int i2 = idx - 36864;
        const int d = i2 / 1344, kp = i2 - d * 1344;
        float v = 0.f;
        if (kp < 160)      v = Wproj_i[(64 + kp) * 64 + d];
        else if (kp < 192) { const int j = kp - 160; if (j < 10) v = Wnum_i[j * 64 + d]; }
        else if (kp < 224) { const int j = kp - 192; if (j < 12) v = Wproj_i[(512 + j) * 64 + d]; }
        else if (kp < 288) v = Wproj_i[(kp - 224) * 64 + d];
        else if (kp < 576) v = Wproj_i[(224 + kp - 288) * 64 + d];
        else               v = Wproj_i[(524 + kp - 576) * 64 + d];
        WTI[d * 1344 + kp] = f2bf(v);
    } else {
        const int i2 = idx - 122880;
        if (i2 < 4096) { const int d = i2 >> 6, k = i2 & 63;  WvT[d * 64 + k]  = f2bf(Wv0[k * 64 + d]); }
        else           { const int j = i2 - 4096;
                         const int d = j >> 7, k = j & 127;   WwT[d * 128 + k] = f2bf(Ww0[k * 64 + d]); }
    }
}

// ---------------------------------------------------------------------------
// gpack: builds the FULL pre-swizzled tiled bf16 A ("Apack") for one type.
// Layout: tile(128 rows) -> chunk(64 cols) -> wave(32 rows) -> row32 ->
//         16B slot at byte ((d0*16) ^ ((r32&7)<<4)).   8 threads per node.
// Chunk->source: 0 feat-mean | 1 text s0/s1 | 2 text s2 + numeric |
//   3 w300-tail + id[0:32) | 4 id[32:64) + w300[0:32) | 5..8 w300[32:288)
//   | 9..20 s768 (items).
// ---------------------------------------------------------------------------
template<int IS_ITEM>
__global__ __launch_bounds__(256) void gpack_kernel(
    const int* __restrict__ fidx_, const int* __restrict__ tidx_,
    const float* __restrict__ fe, const float* __restrict__ wemb,
    const float* __restrict__ idt, const float* __restrict__ w3t,
    const float* __restrict__ s7t, const float* __restrict__ nmt,
    uint16_t* __restrict__ Apack)
{
    constexpr int NTYPE = IS_ITEM ? M_ITEM : N_USER;
    constexpr int NCH   = IS_ITEM ? NCH_I : NCH_U;
    const int gid  = blockIdx.x * 256 + threadIdx.x;
    const int node = gid >> 3;
    const int d0   = gid & 7;
    if (node >= NTYPE) return;
    const int tile = node >> 7, r = node & 127, w = r >> 5, r32 = r & 31;
    char* out = (char*)Apack + (size_t)tile * NCH * 16384 + w * 4096
              + r32 * 128 + ((d0 * 16) ^ ((r32 & 7) << 4));

    const int* fidx = fidx_ + (size_t)node * 10;
    const int* tidx = tidx_ + (size_t)node * 24;
    const float* wr  = w3t + (size_t)node * 300;
    const float* idr = idt + (size_t)node * 64;

    // chunk 0: feat mean, dims d0*8..+8
    {
        f32x4 s0 = {0, 0, 0, 0}, s1 = {0, 0, 0, 0};
#pragma unroll
        for (int j = 0; j < 10; ++j) {
            const float* p = fe + (size_t)fidx[j] * 64 + 8 * d0;
            s0 += *(const f32x4*)p;
            s1 += *(const f32x4*)(p + 4);
        }
        s0 *= 0.1f; s1 *= 0.1f;
        *(uint4*)out = make_uint4(pk2(s0[0], s0[1]), pk2(s0[2], s0[3]),
                                  pk2(s1[0], s1[1]), pk2(s1[2], s1[3]));
    }
    // text gather: 8 dims of one source, mean of 8 rows
    auto text8 = [&](int src, int dd) -> uint4 {
        f32x4 a = {0, 0, 0, 0}, b = {0, 0, 0, 0};
#pragma unroll
        for (int j = 0; j < 8; ++j) {
            const float* p = wemb + (size_t)tidx[src * 8 + j] * 32 + dd;
            a += *(const f32x4*)p;
            b += *(const f32x4*)(p + 4);
        }
        a *= 0.125f; b *= 0.125f;
        return make_uint4(pk2(a[0], a[1]), pk2(a[2], a[3]),
                          pk2(b[0], b[1]), pk2(b[2], b[3]));
    };
    // chunk 1: text src (d0>>2), dims (d0&3)*8
    *(uint4*)(out + 16384) = text8(d0 >> 2, (d0 & 3) * 8);
    // chunk 2: d0<4 -> text src2 dims d0*8 ; else numeric (d0-4)*8 mask<10
    *(uint4*)(out + 2 * 16384) = (d0 < 4)
        ? text8(2, d0 * 8)
        : maskrow(nmt + (size_t)node * 10, (d0 - 4) * 8, 10);
    // chunk 3: d0<4 -> w300 tail (288+d0*8, mask 12) ; else id[(d0-4)*8]
    *(uint4*)(out + 3 * 16384) = (d0 < 4)
        ? maskrow(wr + 288, d0 * 8, 12)
        : packrow(idr + (d0 - 4) * 8);
    // chunk 4: d0<4 -> id[32+d0*8] ; else w300[(d0-4)*8]
    *(uint4*)(out + 4 * 16384) = (d0 < 4)
        ? packrow(idr + 32 + d0 * 8)
        : packrow(wr + (d0 - 4) * 8);
    // chunks 5..8: w300[c*64 + d0*8 - 288]
#pragma unroll
    for (int c = 5; c < 9; ++c)
        *(uint4*)(out + c * 16384) = packrow(wr + c * 64 + d0 * 8 - 288);
    // chunks 9..20: s768 (items)
    if (IS_ITEM) {
        const float* sr = s7t + (size_t)node * 768;
#pragma unroll
        for (int c = 9; c < 21; ++c)
            *(uint4*)(out + c * 16384) = packrow(sr + c * 64 + d0 * 8 - 576);
    }
}

// ---------------------------------------------------------------------------
// pgemm3: m97-shape GEMM over packed A. 128-node tile, BK=64 bf16.
// Per chunk per wave: 4 linear global_load_lds (4KB own rows) + 16 MFMA.
// Double-buffered 32KB LDS, 2-barrier loop. B (WT) from L2 per chunk.
// ---------------------------------------------------------------------------
__global__ __launch_bounds__(256, 4) void pgemm3_kernel(
    const uint16_t* __restrict__ Apack, const uint16_t* __restrict__ WT,
    const float* __restrict__ bp, const float* __restrict__ bn,
    uint16_t* __restrict__ xout, int ntype, int nch, int KP)
{
    __shared__ char lds[2][16384];

    const int t = threadIdx.x;
    const int w = t >> 6, l = t & 63;
    const int l15 = l & 15, g4 = l >> 4;
    const int nb = blockIdx.x * 128;

    f32x4 acc[2][4] = {};
    const uint16_t* WTb = WT + (size_t)l15 * KP + g4 * 8;
    const char* Atile = (const char*)Apack + (size_t)blockIdx.x * nch * 16384;

    auto stage = [&](int bi, int c) {
        const char* src = Atile + c * 16384 + w * 4096 + l * 16;
        char* dst = &lds[bi][w * 4096];
#pragma unroll
        for (int j = 0; j < 4; ++j)
            __builtin_amdgcn_global_load_lds((glb_u32_t*)(src + j * 1024),
                (lds_u32_t*)(void*)(dst + j * 1024), 16, 0, 0);
    };

    auto compute = [&](int bi, int c) {
        const char* wb = &lds[bi][w * 4096];
#pragma unroll
        for (int ks = 0; ks < 2; ++ks) {
            bf16x8 bfr[4];
#pragma unroll
            for (int db = 0; db < 4; ++db)
                bfr[db] = *reinterpret_cast<const bf16x8*>(
                    WTb + (size_t)db * 16 * KP + c * 64 + ks * 32);
#pragma unroll
            for (int frag = 0; frag < 2; ++frag) {
                const int r32 = frag * 16 + l15;
                const bf16x8 af = *(const bf16x8*)(wb + r32 * 128
                    + ((ks * 64 + g4 * 16) ^ ((r32 & 7) << 4)));
#pragma unroll
                for (int db = 0; db < 4; ++db)
                    acc[frag][db] = __builtin_amdgcn_mfma_f32_16x16x32_bf16(
                        af, bfr[db], acc[frag][db], 0, 0, 0);
            }
        }
    };

    stage(0, 0);
#pragma unroll 1
    for (int c = 0; c < nch; ++c) {
        if (c + 1 < nch) stage((c + 1) & 1, c + 1);
        __syncthreads();
        compute(c & 1, c);
        __syncthreads();
    }

    // epilogue: row = nb + w*32 + frag*16 + g4*4 + rr ; col d = db*16 + l15
#pragma unroll
    for (int frag = 0; frag < 2; ++frag) {
        const int rb = nb + w * 32 + frag * 16 + g4 * 4;
#pragma unroll
        for (int db = 0; db < 4; ++db) {
            const int d = db * 16 + l15;
            const float bias = bp[d] + bn[d];
#pragma unroll
            for (int rr = 0; rr < 4; ++rr) {
                const int nn = rb + rr;
                if (nn < ntype) xout[(size_t)nn * 64 + d] = f2bf(acc[frag][db][rr] + bias);
            }
        }
    }
}

// ---------------------------------------------------------------------------
// xv = x @ Wv0 + bv0   (bf16 in/out, per node)
// ---------------------------------------------------------------------------
__global__ __launch_bounds__(256) void xv_kernel(
    const uint16_t* __restrict__ x, const uint16_t* __restrict__ WvT,
    const float* __restrict__ bv, uint16_t* __restrict__ xv, int n)
{
    const int t = threadIdx.x;
    const int w = t >> 6, l = t & 63, l15 = l & 15, g4 = l >> 4;
    const int node = blockIdx.x * 64 + w * 16 + l15;
    const int node_c = node < n ? node : n - 1;

    f32x4 acc[4] = {};
    const uint16_t* WTb = WvT + l15 * 64 + g4 * 8;
#pragma unroll
    for (int ks = 0; ks < 2; ++ks) {
        const bf16x8 af = *reinterpret_cast<const bf16x8*>(x + (size_t)node_c * 64 + ks * 32 + g4 * 8);
#pragma unroll
        for (int db = 0; db < 4; ++db) {
            const bf16x8 bfr = *reinterpret_cast<const bf16x8*>(WTb + db * 16 * 64 + ks * 32);
            acc[db] = __builtin_amdgcn_mfma_f32_16x16x32_bf16(af, bfr, acc[db], 0, 0, 0);
        }
    }
    const int node_base = blockIdx.x * 64 + w * 16 + g4 * 4;
#pragma unroll
    for (int db = 0; db < 4; ++db) {
        const int d = db * 16 + l15;
        const float bias = bv[d];
#pragma unroll
        for (int r = 0; r < 4; ++r) {
            const int nn = node_base + r;
            if (nn < n) xv[(size_t)nn * 64 + d] = f2bf(acc[db][r] + bias);
        }
    }
}

// ---------------------------------------------------------------------------
// Fused SAGE layer-0 (h1 rows [0,40960), h0 rows [40960,43008))
// ---------------------------------------------------------------------------
__global__ __launch_bounds__(256) void sage_fused_kernel(
    const uint16_t* __restrict__ x, const uint16_t* __restrict__ xv,
    const int* __restrict__ seeds, const int* __restrict__ neigh1,
    const int* __restrict__ neigh2,
    const uint16_t* __restrict__ WwT, const float* __restrict__ bw,
    uint16_t* __restrict__ h1, uint16_t* __restrict__ h0)
{
    const int t = threadIdx.x;
    const int w = t >> 6, l = t & 63, l15 = l & 15, g4 = l >> 4;
    const int rbase = blockIdx.x * 64 + w * 16;
    const bool is1 = rbase < 40960;               // wave-uniform
    const int r = rbase + l15;
    const int sidx = is1 ? neigh1[r] : seeds[r - 40960];
    const int* ni = is1 ? (neigh2 + (size_t)r * S_NB)
                        : (neigh1 + (size_t)(r - 40960) * S_NB);

    f32x4 acc[4] = {};
    const uint16_t* WTb = WwT + l15 * 128 + g4 * 8;

    auto MM = [&](bf16x8 af, int kb) {
#pragma unroll
        for (int db = 0; db < 4; ++db) {
            const bf16x8 bfr = *reinterpret_cast<const bf16x8*>(WTb + db * 16 * 128 + kb);
            acc[db] = __builtin_amdgcn_mfma_f32_16x16x32_bf16(af, bfr, acc[db], 0, 0, 0);
        }
    };

#pragma unroll
    for (int ks = 0; ks < 2; ++ks) {
        const bf16x8 af = *reinterpret_cast<const bf16x8*>(x + (size_t)sidx * 64 + ks * 32 + g4 * 8);
        MM(af, ks * 32);
    }
#pragma unroll
    for (int ks = 0; ks < 2; ++ks) {
        float ev[4] = {0.f, 0.f, 0.f, 0.f}, od[4] = {0.f, 0.f, 0.f, 0.f};
#pragma unroll
        for (int j = 0; j < S_NB; ++j) {
            const u32x4 v = *reinterpret_cast<const u32x4*>(xv + (size_t)ni[j] * 64 + ks * 32 + g4 * 8);
#pragma unroll
            for (int q = 0; q < 4; ++q) {
                ev[q] += __uint_as_float(v[q] << 16);
                od[q] += __uint_as_float(v[q] & 0xffff0000u);
            }
        }
        BF8 m;
#pragma unroll
        for (int q = 0; q < 4; ++q) m.u[q] = pk2(ev[q] * (1.f / S_NB), od[q] * (1.f / S_NB));
        MM(m.v, 64 + ks * 32);
    }

    const int rb = blockIdx.x * 64 + w * 16 + g4 * 4;
    uint16_t* ob = is1 ? h1 : h0;
    const int rowoff = is1 ? 0 : 40960;
#pragma unroll
    for (int db = 0; db < 4; ++db) {
        const int d = db * 16 + l15;
        const float bias = bw[d];
#pragma unroll
        for (int rr = 0; rr < 4; ++rr) {
            const float h = fmaxf(acc[db][rr] + bias, 0.f);
            ob[(size_t)(rb + rr - rowoff) * 64 + d] = f2bf(h);
        }
    }
}

// ---------------------------------------------------------------------------
// Final layer (fp32 shfl GEMV, 2048 rows)
// ---------------------------------------------------------------------------
__global__ __launch_bounds__(256) void final_kernel(
    const uint16_t* __restrict__ h0, const uint16_t* __restrict__ h1,
    const float* __restrict__ Wv, const float* __restrict__ bv,
    const float* __restrict__ Ww, const float* __restrict__ bw,
    float* __restrict__ out)
{
    __shared__ float WvL[64 * 64];
    __shared__ float WwL[128 * 64];
    const int t = threadIdx.x;
    for (int i = t; i < 64 * 64; i += 256)  WvL[i] = Wv[i];
    for (int i = t; i < 128 * 64; i += 256) WwL[i] = Ww[i];
    __syncthreads();

    const int wave = t >> 6, lane = t & 63;
    const int base = blockIdx.x * 32 + wave * 8;
    const float bvl = bv[lane], bwl = bw[lane];

    for (int i = 0; i < 8; ++i) {
        const int b = base + i;
        float m = 0.f;
#pragma unroll
        for (int s = 0; s < S_NB; ++s)
            m += bf2f(h1[(size_t)(b * S_NB + s) * 64 + lane]);
        m *= (1.f / S_NB);

        float agg = bvl;
#pragma unroll 8
        for (int k = 0; k < 64; ++k)
            agg += __shfl(m, k) * WvL[k * 64 + lane];

        const float selfv = bf2f(h0[(size_t)b * 64 + lane]);
        float h = bwl;
#pragma unroll 8
        for (int k = 0; k < 64; ++k)
            h += __shfl(selfv, k) * WwL[k * 64 + lane];
#pragma unroll 8
        for (int k = 0; k < 64; ++k)
            h += __shfl(agg, k) * WwL[(64 + k) * 64 + lane];

        out[(size_t)b * 64 + lane] = h;
    }
}

// ---------------------------------------------------------------------------
extern "C" void kernel_launch(void* const* d_in, const int* in_sizes, int n_in,
                              void* d_out, int out_size, void* d_ws, size_t ws_size,
                              hipStream_t stream)
{
    const int*   seeds   = (const int*)d_in[0];
    const int*   neigh1  = (const int*)d_in[1];
    const int*   neigh2  = (const int*)d_in[2];
    const int*   ufi     = (const int*)d_in[3];
    const int*   ifi     = (const int*)d_in[4];
    const int*   uti     = (const int*)d_in[5];
    const int*   iti     = (const int*)d_in[6];
    const float* u_id    = (const float*)d_in[7];
    const float* i_id    = (const float*)d_in[8];
    const float* ufe     = (const float*)d_in[9];
    const float* ife     = (const float*)d_in[10];
    const float* wemb    = (const float*)d_in[11];
    const float* uw300   = (const float*)d_in[12];
    const float* iw300   = (const float*)d_in[13];
    const float* is768   = (const float*)d_in[14];
    const float* unum    = (const float*)d_in[15];
    const float* inum    = (const float*)d_in[16];
    const float* Wnum_u  = (const float*)d_in[17];
    const float* bnum_u  = (const float*)d_in[18];
    const float* Wnum_i  = (const float*)d_in[19];
    const float* bnum_i  = (const float*)d_in[20];
    const float* Wproj_u = (const float*)d_in[21];
    const float* bproj_u = (const float*)d_in[22];
    const float* Wproj_i = (const float*)d_in[23];
    const float* bproj_i = (const float*)d_in[24];
    const float* W_w     = (const float*)d_in[25];
    const float* b_w     = (const float*)d_in[26];
    const float* W_v     = (const float*)d_in[27];
    const float* b_v     = (const float*)d_in[28];

    // ws layout (uint16 elements):
    // WTU | WTI | WvT0 | WwT0 | xbf | REGION{ Apack (135MB, dead after pgemm3)
    //                                         ∪ (xvbf | h1bf | h0bf) }
    uint16_t* WTU  = (uint16_t*)d_ws;                       // 64*576
    uint16_t* WTI  = WTU  + 36864;                          // 64*1344
    uint16_t* WvT0 = WTI  + 86016;                          // 64*64
    uint16_t* WwT0 = WvT0 + 4096;                           // 64*128
    uint16_t* xbf  = WwT0 + 8192;                           // 150000*64
    uint16_t* region = xbf + (size_t)N_NODE * 64;
    uint16_t* Apack = region;                               // max(TILES_I*21, TILES_U*9)*8192 u16
    uint16_t* xvbf  = region;                               // alias (used after pgemm3)
    uint16_t* h1bf  = xvbf + (size_t)N_NODE * 64;
    uint16_t* h0bf  = h1bf + (size_t)B_SEED * S_NB * 64;
    float* outp = (float*)d_out;

    prep_kernel<<<528, 256, 0, stream>>>(
        Wproj_u, Wnum_u, Wproj_i, Wnum_i, W_v, W_w, WTU, WTI, WvT0, WwT0);

    // users: pack -> gemm
    gpack_kernel<0><<<(N_USER * 8) / 256, 256, 0, stream>>>(
        ufi, uti, ufe, wemb, u_id, uw300, nullptr, unum, Apack);
    pgemm3_kernel<<<TILES_U, 256, 0, stream>>>(
        Apack, WTU, bproj_u, bnum_u, xbf, N_USER, NCH_U, 576);

    // items: pack -> gemm (reuses Apack region)
    gpack_kernel<1><<<(M_ITEM * 8 + 255) / 256, 256, 0, stream>>>(
        ifi, iti, ife, wemb, i_id, iw300, is768, inum, Apack);
    pgemm3_kernel<<<TILES_I, 256, 0, stream>>>(
        Apack, WTI, bproj_i, bnum_i, xbf + (size_t)N_USER * 64, M_ITEM, NCH_I, 1344);

    xv_kernel<<<(N_NODE + 63) / 64, 256, 0, stream>>>(xbf, WvT0, b_v, xvbf, N_NODE);

    sage_fused_kernel<<<672, 256, 0, stream>>>(
        xbf, xvbf, seeds, neigh1, neigh2, WwT0, b_w, h1bf, h0bf);

    final_kernel<<<B_SEED / 32, 256, 0, stream>>>(
        h0bf, h1bf, W_v + 4096, b_v + 64, W_w + 8192, b_w + 64, outp);
}

// Round 16
// 387.144 us; speedup vs baseline: 1.0023x; 1.0023x over previous
//
#include <hip/hip_runtime.h>
#include <hip/hip_bf16.h>
#include <stdint.h>

#define N_USER 100000
#define M_ITEM 50000
#define N_NODE 150000
#define B_SEED 2048
#define S_NB 20
#define TILES_U 782          // ceil(100000/128)
#define TILES_I 391          // ceil(50000/128)
#define NCH_U 9              // 576 cols / 64
#define NCH_I 21             // 1344 cols / 64

typedef __bf16   bf16x8 __attribute__((ext_vector_type(8)));
typedef float    f32x4  __attribute__((ext_vector_type(4)));
typedef uint32_t u32x4  __attribute__((ext_vector_type(4)));

typedef __attribute__((address_space(3))) uint32_t lds_u32_t;
typedef __attribute__((address_space(1))) const uint32_t glb_u32_t;

__device__ __forceinline__ uint16_t f2bf(float f) {
    uint32_t u = __float_as_uint(f);
    return (uint16_t)((u + 0x7FFFu + ((u >> 16) & 1u)) >> 16);   // RNE
}
__device__ __forceinline__ uint32_t pk2(float a, float b) {      // packed HW cvt (RNE)
    __hip_bfloat162 h = __float22bfloat162_rn(make_float2(a, b));
    return *reinterpret_cast<uint32_t*>(&h);
}
__device__ __forceinline__ float bf2f(uint16_t u) {
    return __uint_as_float(((uint32_t)u) << 16);
}

union BF8 { bf16x8 v; uint32_t u[4]; };

__device__ __forceinline__ uint4 packrow(const float* p) {
    const f32x4 a = *(const f32x4*)p, b = *(const f32x4*)(p + 4);
    return make_uint4(pk2(a[0], a[1]), pk2(a[2], a[3]),
                      pk2(b[0], b[1]), pk2(b[2], b[3]));
}
__device__ __forceinline__ uint4 maskrow(const float* p, int j0, int lim) {
    float v[8];
#pragma unroll
    for (int h = 0; h < 8; ++h) v[h] = (j0 + h < lim) ? p[j0 + h] : 0.f;
    return make_uint4(pk2(v[0], v[1]), pk2(v[2], v[3]),
                      pk2(v[4], v[5]), pk2(v[6], v[7]));
}

// ---------------------------------------------------------------------------
// prep: permuted-K transposed weights (bf16). k' order (matches Apack cols):
// [0,64) feat | [64,160) text | [160,192) numeric(10) | [192,224) w300 tail(12)
// [224,288) id | [288,576) w300 0..287 | [576,1344) s768 (items)
// ---------------------------------------------------------------------------
__global__ void prep_kernel(const float* __restrict__ Wproj_u, const float* __restrict__ Wnum_u,
                            const float* __restrict__ Wproj_i, const float* __restrict__ Wnum_i,
                            const float* __restrict__ Wv0, const float* __restrict__ Ww0,
                            uint16_t* __restrict__ WTU, uint16_t* __restrict__ WTI,
                            uint16_t* __restrict__ WvT, uint16_t* __restrict__ WwT)
{
    const int idx = blockIdx.x * 256 + threadIdx.x;   // exactly 135168
    if (idx < 36864) {
        const int d = idx / 576, kp = idx - d * 576;
        float v = 0.f;
        if (kp < 160)      v = Wproj_u[(64 + kp) * 64 + d];
        else if (kp < 192) { const int j = kp - 160; if (j < 10) v = Wnum_u[j * 64 + d]; }
        else if (kp < 224) { const int j = kp - 192; if (j < 12) v = Wproj_u[(512 + j) * 64 + d]; }
        else if (kp < 288) v = Wproj_u[(kp - 224) * 64 + d];
        else               v = Wproj_u[(224 + kp - 288) * 64 + d];
        WTU[d * 576 + kp] = f2bf(v);
    } else if (idx < 122880) {
        const int i2 = idx - 36864;
        const int d = i2 / 1344, kp = i2 - d * 1344;
        float v = 0.f;
        if (kp < 160)      v = Wproj_i[(64 + kp) * 64 + d];
        else if (kp < 192) { const int j = kp - 160; if (j < 10) v = Wnum_i[j * 64 + d]; }
        else if (kp < 224) { const int j = kp - 192; if (j < 12) v = Wproj_i[(512 + j) * 64 + d]; }
        else if (kp < 288) v = Wproj_i[(kp - 224) * 64 + d];
        else if (kp < 576) v = Wproj_i[(224 + kp - 288) * 64 + d];
        else               v = Wproj_i[(524 + kp - 576) * 64 + d];
        WTI[d * 1344 + kp] = f2bf(v);
    } else {
        const int i2 = idx - 122880;
        if (i2 < 4096) { const int d = i2 >> 6, k = i2 & 63;  WvT[d * 64 + k]  = f2bf(Wv0[k * 64 + d]); }
        else           { const int j = i2 - 4096;
                         const int d = j >> 7, k = j & 127;   WwT[d * 128 + k] = f2bf(Ww0[k * 64 + d]); }
    }
}

// ---------------------------------------------------------------------------
// gpack: builds the FULL pre-swizzled tiled bf16 A ("Apack") for one type.
// Layout: tile(128 rows) -> chunk(64 cols) -> wave(32 rows) -> row32 ->
//         16B slot at byte ((d0*16) ^ ((r32&7)<<4)).   8 threads per node.
// Chunk->source: 0 feat-mean | 1 text s0/s1 | 2 text s2 + numeric |
//   3 w300-tail + id[0:32) | 4 id[32:64) + w300[0:32) | 5..8 w300[32:288)
//   | 9..20 s768 (items).
// ---------------------------------------------------------------------------
template<int IS_ITEM>
__global__ __launch_bounds__(256) void gpack_kernel(
    const int* __restrict__ fidx_, const int* __restrict__ tidx_,
    const float* __restrict__ fe, const float* __restrict__ wemb,
    const float* __restrict__ idt, const float* __restrict__ w3t,
    const float* __restrict__ s7t, const float* __restrict__ nmt,
    uint16_t* __restrict__ Apack)
{
    constexpr int NTYPE = IS_ITEM ? M_ITEM : N_USER;
    constexpr int NCH   = IS_ITEM ? NCH_I : NCH_U;
    const int gid  = blockIdx.x * 256 + threadIdx.x;
    const int node = gid >> 3;
    const int d0   = gid & 7;
    if (node >= NTYPE) return;
    const int tile = node >> 7, r = node & 127, w = r >> 5, r32 = r & 31;
    char* out = (char*)Apack + (size_t)tile * NCH * 16384 + w * 4096
              + r32 * 128 + ((d0 * 16) ^ ((r32 & 7) << 4));

    const int* fidx = fidx_ + (size_t)node * 10;
    const int* tidx = tidx_ + (size_t)node * 24;
    const float* wr  = w3t + (size_t)node * 300;
    const float* idr = idt + (size_t)node * 64;

    // chunk 0: feat mean, dims d0*8..+8
    {
        f32x4 s0 = {0, 0, 0, 0}, s1 = {0, 0, 0, 0};
#pragma unroll
        for (int j = 0; j < 10; ++j) {
            const float* p = fe + (size_t)fidx[j] * 64 + 8 * d0;
            s0 += *(const f32x4*)p;
            s1 += *(const f32x4*)(p + 4);
        }
        s0 *= 0.1f; s1 *= 0.1f;
        *(uint4*)out = make_uint4(pk2(s0[0], s0[1]), pk2(s0[2], s0[3]),
                                  pk2(s1[0], s1[1]), pk2(s1[2], s1[3]));
    }
    // text gather: 8 dims of one source, mean of 8 rows
    auto text8 = [&](int src, int dd) -> uint4 {
        f32x4 a = {0, 0, 0, 0}, b = {0, 0, 0, 0};
#pragma unroll
        for (int j = 0; j < 8; ++j) {
            const float* p = wemb + (size_t)tidx[src * 8 + j] * 32 + dd;
            a += *(const f32x4*)p;
            b += *(const f32x4*)(p + 4);
        }
        a *= 0.125f; b *= 0.125f;
        return make_uint4(pk2(a[0], a[1]), pk2(a[2], a[3]),
                          pk2(b[0], b[1]), pk2(b[2], b[3]));
    };
    // chunk 1: text src (d0>>2), dims (d0&3)*8
    *(uint4*)(out + 16384) = text8(d0 >> 2, (d0 & 3) * 8);
    // chunk 2: d0<4 -> text src2 dims d0*8 ; else numeric (d0-4)*8 mask<10
    *(uint4*)(out + 2 * 16384) = (d0 < 4)
        ? text8(2, d0 * 8)
        : maskrow(nmt + (size_t)node * 10, (d0 - 4) * 8, 10);
    // chunk 3: d0<4 -> w300 tail (288+d0*8, mask 12) ; else id[(d0-4)*8]
    *(uint4*)(out + 3 * 16384) = (d0 < 4)
        ? maskrow(wr + 288, d0 * 8, 12)
        : packrow(idr + (d0 - 4) * 8);
    // chunk 4: d0<4 -> id[32+d0*8] ; else w300[(d0-4)*8]
    *(uint4*)(out + 4 * 16384) = (d0 < 4)
        ? packrow(idr + 32 + d0 * 8)
        : packrow(wr + (d0 - 4) * 8);
    // chunks 5..8: w300[c*64 + d0*8 - 288]
#pragma unroll
    for (int c = 5; c < 9; ++c)
        *(uint4*)(out + c * 16384) = packrow(wr + c * 64 + d0 * 8 - 288);
    // chunks 9..20: s768 (items)
    if (IS_ITEM) {
        const float* sr = s7t + (size_t)node * 768;
#pragma unroll
        for (int c = 9; c < 21; ++c)
            *(uint4*)(out + c * 16384) = packrow(sr + c * 64 + d0 * 8 - 576);
    }
}

// ---------------------------------------------------------------------------
// pgemm3: m97-shape GEMM over packed A. 128-node tile, BK=64 bf16.
// Per chunk per wave: 4 linear global_load_lds (4KB own rows) + 16 MFMA.
// Double-buffered 32KB LDS, 2-barrier loop. B (WT) from L2 per chunk.
// ---------------------------------------------------------------------------
__global__ __launch_bounds__(256, 4) void pgemm3_kernel(
    const uint16_t* __restrict__ Apack, const uint16_t* __restrict__ WT,
    const float* __restrict__ bp, const float* __restrict__ bn,
    uint16_t* __restrict__ xout, int ntype, int nch, int KP)
{
    __shared__ char lds[2][16384];

    const int t = threadIdx.x;
    const int w = t >> 6, l = t & 63;
    const int l15 = l & 15, g4 = l >> 4;
    const int nb = blockIdx.x * 128;

    f32x4 acc[2][4] = {};
    const uint16_t* WTb = WT + (size_t)l15 * KP + g4 * 8;
    const char* Atile = (const char*)Apack + (size_t)blockIdx.x * nch * 16384;

    auto stage = [&](int bi, int c) {
        const char* src = Atile + c * 16384 + w * 4096 + l * 16;
        char* dst = &lds[bi][w * 4096];
#pragma unroll
        for (int j = 0; j < 4; ++j)
            __builtin_amdgcn_global_load_lds((glb_u32_t*)(src + j * 1024),
                (lds_u32_t*)(void*)(dst + j * 1024), 16, 0, 0);
    };

    auto compute = [&](int bi, int c) {
        const char* wb = &lds[bi][w * 4096];
#pragma unroll
        for (int ks = 0; ks < 2; ++ks) {
            bf16x8 bfr[4];
#pragma unroll
            for (int db = 0; db < 4; ++db)
                bfr[db] = *reinterpret_cast<const bf16x8*>(
                    WTb + (size_t)db * 16 * KP + c * 64 + ks * 32);
#pragma unroll
            for (int frag = 0; frag < 2; ++frag) {
                const int r32 = frag * 16 + l15;
                const bf16x8 af = *(const bf16x8*)(wb + r32 * 128
                    + ((ks * 64 + g4 * 16) ^ ((r32 & 7) << 4)));
#pragma unroll
                for (int db = 0; db < 4; ++db)
                    acc[frag][db] = __builtin_amdgcn_mfma_f32_16x16x32_bf16(
                        af, bfr[db], acc[frag][db], 0, 0, 0);
            }
        }
    };

    stage(0, 0);
#pragma unroll 1
    for (int c = 0; c < nch; ++c) {
        if (c + 1 < nch) stage((c + 1) & 1, c + 1);
        __syncthreads();
        compute(c & 1, c);
        __syncthreads();
    }

    // epilogue: row = nb + w*32 + frag*16 + g4*4 + rr ; col d = db*16 + l15
#pragma unroll
    for (int frag = 0; frag < 2; ++frag) {
        const int rb = nb + w * 32 + frag * 16 + g4 * 4;
#pragma unroll
        for (int db = 0; db < 4; ++db) {
            const int d = db * 16 + l15;
            const float bias = bp[d] + bn[d];
#pragma unroll
            for (int rr = 0; rr < 4; ++rr) {
                const int nn = rb + rr;
                if (nn < ntype) xout[(size_t)nn * 64 + d] = f2bf(acc[frag][db][rr] + bias);
            }
        }
    }
}

// ---------------------------------------------------------------------------
// xv = x @ Wv0 + bv0   (bf16 in/out, per node)
// ---------------------------------------------------------------------------
__global__ __launch_bounds__(256) void xv_kernel(
    const uint16_t* __restrict__ x, const uint16_t* __restrict__ WvT,
    const float* __restrict__ bv, uint16_t* __restrict__ xv, int n)
{
    const int t = threadIdx.x;
    const int w = t >> 6, l = t & 63, l15 = l & 15, g4 = l >> 4;
    const int node = blockIdx.x * 64 + w * 16 + l15;
    const int node_c = node < n ? node : n - 1;

    f32x4 acc[4] = {};
    const uint16_t* WTb = WvT + l15 * 64 + g4 * 8;
#pragma unroll
    for (int ks = 0; ks < 2; ++ks) {
        const bf16x8 af = *reinterpret_cast<const bf16x8*>(x + (size_t)node_c * 64 + ks * 32 + g4 * 8);
#pragma unroll
        for (int db = 0; db < 4; ++db) {
            const bf16x8 bfr = *reinterpret_cast<const bf16x8*>(WTb + db * 16 * 64 + ks * 32);
            acc[db] = __builtin_amdgcn_mfma_f32_16x16x32_bf16(af, bfr, acc[db], 0, 0, 0);
        }
    }
    const int node_base = blockIdx.x * 64 + w * 16 + g4 * 4;
#pragma unroll
    for (int db = 0; db < 4; ++db) {
        const int d = db * 16 + l15;
        const float bias = bv[d];
#pragma unroll
        for (int r = 0; r < 4; ++r) {
            const int nn = node_base + r;
            if (nn < n) xv[(size_t)nn * 64 + d] = f2bf(acc[db][r] + bias);
        }
    }
}

// ---------------------------------------------------------------------------
// Fused SAGE layer-0 (h1 rows [0,40960), h0 rows [40960,43008))
// ---------------------------------------------------------------------------
__global__ __launch_bounds__(256) void sage_fused_kernel(
    const uint16_t* __restrict__ x, const uint16_t* __restrict__ xv,
    const int* __restrict__ seeds, const int* __restrict__ neigh1,
    const int* __restrict__ neigh2,
    const uint16_t* __restrict__ WwT, const float* __restrict__ bw,
    uint16_t* __restrict__ h1, uint16_t* __restrict__ h0)
{
    const int t = threadIdx.x;
    const int w = t >> 6, l = t & 63, l15 = l & 15, g4 = l >> 4;
    const int rbase = blockIdx.x * 64 + w * 16;
    const bool is1 = rbase < 40960;               // wave-uniform
    const int r = rbase + l15;
    const int sidx = is1 ? neigh1[r] : seeds[r - 40960];
    const int* ni = is1 ? (neigh2 + (size_t)r * S_NB)
                        : (neigh1 + (size_t)(r - 40960) * S_NB);

    f32x4 acc[4] = {};
    const uint16_t* WTb = WwT + l15 * 128 + g4 * 8;

    auto MM = [&](bf16x8 af, int kb) {
#pragma unroll
        for (int db = 0; db < 4; ++db) {
            const bf16x8 bfr = *reinterpret_cast<const bf16x8*>(WTb + db * 16 * 128 + kb);
            acc[db] = __builtin_amdgcn_mfma_f32_16x16x32_bf16(af, bfr, acc[db], 0, 0, 0);
        }
    };

#pragma unroll
    for (int ks = 0; ks < 2; ++ks) {
        const bf16x8 af = *reinterpret_cast<const bf16x8*>(x + (size_t)sidx * 64 + ks * 32 + g4 * 8);
        MM(af, ks * 32);
    }
#pragma unroll
    for (int ks = 0; ks < 2; ++ks) {
        float ev[4] = {0.f, 0.f, 0.f, 0.f}, od[4] = {0.f, 0.f, 0.f, 0.f};
#pragma unroll
        for (int j = 0; j < S_NB; ++j) {
            const u32x4 v = *reinterpret_cast<const u32x4*>(xv + (size_t)ni[j] * 64 + ks * 32 + g4 * 8);
#pragma unroll
            for (int q = 0; q < 4; ++q) {
                ev[q] += __uint_as_float(v[q] << 16);
                od[q] += __uint_as_float(v[q] & 0xffff0000u);
            }
        }
        BF8 m;
#pragma unroll
        for (int q = 0; q < 4; ++q) m.u[q] = pk2(ev[q] * (1.f / S_NB), od[q] * (1.f / S_NB));
        MM(m.v, 64 + ks * 32);
    }

    const int rb = blockIdx.x * 64 + w * 16 + g4 * 4;
    uint16_t* ob = is1 ? h1 : h0;
    const int rowoff = is1 ? 0 : 40960;
#pragma unroll
    for (int db = 0; db < 4; ++db) {
        const int d = db * 16 + l15;
        const float bias = bw[d];
#pragma unroll
        for (int rr = 0; rr < 4; ++rr) {
            const float h = fmaxf(acc[db][rr] + bias, 0.f);
            ob[(size_t)(rb + rr - rowoff) * 64 + d] = f2bf(h);
        }
    }
}

// ---------------------------------------------------------------------------
// Final layer (fp32 shfl GEMV, 2048 rows)
// ---------------------------------------------------------------------------
__global__ __launch_bounds__(256) void final_kernel(
    const uint16_t* __restrict__ h0, const uint16_t* __restrict__ h1,
    const float* __restrict__ Wv, const float* __restrict__ bv,
    const float* __restrict__ Ww, const float* __restrict__ bw,
    float* __restrict__ out)
{
    __shared__ float WvL[64 * 64];
    __shared__ float WwL[128 * 64];
    const int t = threadIdx.x;
    for (int i = t; i < 64 * 64; i += 256)  WvL[i] = Wv[i];
    for (int i = t; i < 128 * 64; i += 256) WwL[i] = Ww[i];
    __syncthreads();

    const int wave = t >> 6, lane = t & 63;
    const int base = blockIdx.x * 32 + wave * 8;
    const float bvl = bv[lane], bwl = bw[lane];

    for (int i = 0; i < 8; ++i) {
        const int b = base + i;
        float m = 0.f;
#pragma unroll
        for (int s = 0; s < S_NB; ++s)
            m += bf2f(h1[(size_t)(b * S_NB + s) * 64 + lane]);
        m *= (1.f / S_NB);

        float agg = bvl;
#pragma unroll 8
        for (int k = 0; k < 64; ++k)
            agg += __shfl(m, k) * WvL[k * 64 + lane];

        const float selfv = bf2f(h0[(size_t)b * 64 + lane]);
        float h = bwl;
#pragma unroll 8
        for (int k = 0; k < 64; ++k)
            h += __shfl(selfv, k) * WwL[k * 64 + lane];
#pragma unroll 8
        for (int k = 0; k < 64; ++k)
            h += __shfl(agg, k) * WwL[(64 + k) * 64 + lane];

        out[(size_t)b * 64 + lane] = h;
    }
}

// ---------------------------------------------------------------------------
extern "C" void kernel_launch(void* const* d_in, const int* in_sizes, int n_in,
                              void* d_out, int out_size, void* d_ws, size_t ws_size,
                              hipStream_t stream)
{
    const int*   seeds   = (const int*)d_in[0];
    const int*   neigh1  = (const int*)d_in[1];
    const int*   neigh2  = (const int*)d_in[2];
    const int*   ufi     = (const int*)d_in[3];
    const int*   ifi     = (const int*)d_in[4];
    const int*   uti     = (const int*)d_in[5];
    const int*   iti     = (const int*)d_in[6];
    const float* u_id    = (const float*)d_in[7];
    const float* i_id    = (const float*)d_in[8];
    const float* ufe     = (const float*)d_in[9];
    const float* ife     = (const float*)d_in[10];
    const float* wemb    = (const float*)d_in[11];
    const float* uw300   = (const float*)d_in[12];
    const float* iw300   = (const float*)d_in[13];
    const float* is768   = (const float*)d_in[14];
    const float* unum    = (const float*)d_in[15];
    const float* inum    = (const float*)d_in[16];
    const float* Wnum_u  = (const float*)d_in[17];
    const float* bnum_u  = (const float*)d_in[18];
    const float* Wnum_i  = (const float*)d_in[19];
    const float* bnum_i  = (const float*)d_in[20];
    const float* Wproj_u = (const float*)d_in[21];
    const float* bproj_u = (const float*)d_in[22];
    const float* Wproj_i = (const float*)d_in[23];
    const float* bproj_i = (const float*)d_in[24];
    const float* W_w     = (const float*)d_in[25];
    const float* b_w     = (const float*)d_in[26];
    const float* W_v     = (const float*)d_in[27];
    const float* b_v     = (const float*)d_in[28];

    // ws layout (uint16 elements):
    // WTU | WTI | WvT0 | WwT0 | xbf | REGION{ Apack (135MB, dead after pgemm3)
    //                                         ∪ (xvbf | h1bf | h0bf) }
    uint16_t* WTU  = (uint16_t*)d_ws;                       // 64*576
    uint16_t* WTI  = WTU  + 36864;                          // 64*1344
    uint16_t* WvT0 = WTI  + 86016;                          // 64*64
    uint16_t* WwT0 = WvT0 + 4096;                           // 64*128
    uint16_t* xbf  = WwT0 + 8192;                           // 150000*64
    uint16_t* region = xbf + (size_t)N_NODE * 64;
    uint16_t* Apack = region;                               // max(TILES_I*21, TILES_U*9)*8192 u16
    uint16_t* xvbf  = region;                               // alias (used after pgemm3)
    uint16_t* h1bf  = xvbf + (size_t)N_NODE * 64;
    uint16_t* h0bf  = h1bf + (size_t)B_SEED * S_NB * 64;
    float* outp = (float*)d_out;

    prep_kernel<<<528, 256, 0, stream>>>(
        Wproj_u, Wnum_u, Wproj_i, Wnum_i, W_v, W_w, WTU, WTI, WvT0, WwT0);

    // users: pack -> gemm
    gpack_kernel<0><<<(N_USER * 8) / 256, 256, 0, stream>>>(
        ufi, uti, ufe, wemb, u_id, uw300, nullptr, unum, Apack);
    pgemm3_kernel<<<TILES_U, 256, 0, stream>>>(
        Apack, WTU, bproj_u, bnum_u, xbf, N_USER, NCH_U, 576);

    // items: pack -> gemm (reuses Apack region)
    gpack_kernel<1><<<(M_ITEM * 8 + 255) / 256, 256, 0, stream>>>(
        ifi, iti, ife, wemb, i_id, iw300, is768, inum, Apack);
    pgemm3_kernel<<<TILES_I, 256, 0, stream>>>(
        Apack, WTI, bproj_i, bnum_i, xbf + (size_t)N_USER * 64, M_ITEM, NCH_I, 1344);

    xv_kernel<<<(N_NODE + 63) / 64, 256, 0, stream>>>(xbf, WvT0, b_v, xvbf, N_NODE);

    sage_fused_kernel<<<672, 256, 0, stream>>>(
        xbf, xvbf, seeds, neigh1, neigh2, WwT0, b_w, h1bf, h0bf);

    final_kernel<<<B_SEED / 32, 256, 0, stream>>>(
        h0bf, h1bf, W_v + 4096, b_v + 64, W_w + 8192, b_w + 64, outp);
}